// Round 5
// baseline (406.678 us; speedup 1.0000x reference)
//
#include <hip/hip_runtime.h>
#include <stdint.h>

#define LAMBDA_INIT_F 0.7836057665f   // 0.8 - 0.6*exp(-0.3*12)

typedef __bf16 bf16x8 __attribute__((ext_vector_type(8)));
typedef float  f32x4  __attribute__((ext_vector_type(4)));
typedef unsigned short u16x8 __attribute__((ext_vector_type(8)));
typedef unsigned short u16x4 __attribute__((ext_vector_type(4)));
typedef short s16x4 __attribute__((ext_vector_type(4)));

__device__ __forceinline__ unsigned short f2b(float f) {
    union { float f; unsigned u; } v; v.f = f;
    unsigned u = v.u;
    return (unsigned short)((u + 0x7fffu + ((u >> 16) & 1u)) >> 16);
}

// pack two fp32 -> two bf16 (truncate) in one dword: [bf(b):bf(a)] — P-only, bias cancels in softmax ratio
__device__ __forceinline__ unsigned pk2t(float a, float b) {
    return __builtin_amdgcn_perm(__float_as_uint(b), __float_as_uint(a), 0x07060302u);
}

#if __has_builtin(__builtin_amdgcn_exp2f)
#define EXP2(x) __builtin_amdgcn_exp2f(x)
#else
__device__ __forceinline__ float EXP2(float x) {
    float r; asm volatile("v_exp_f32 %0, %1\n\ts_nop 1" : "=v"(r) : "v"(x)); return r;
}
#endif

// global(16B/lane) -> LDS direct. LDS base must be wave-uniform; lanes land at base + lane*16.
#define GLD16(gp, sp) __builtin_amdgcn_global_load_lds( \
    (const __attribute__((address_space(1))) void*)(uintptr_t)(gp), \
    (__attribute__((address_space(3))) void*)(uint32_t)(uintptr_t)(sp), 16, 0, 0)

// ---------------- fp32 -> bf16 convert, 7 slabs of 4M elements ----------------
__global__ __launch_bounds__(256) void cvt7(const float* __restrict__ s0, const float* __restrict__ s1,
                                            const float* __restrict__ s2, const float* __restrict__ s3,
                                            const float* __restrict__ s4, const float* __restrict__ s5,
                                            const float* __restrict__ s6,
                                            unsigned short* __restrict__ dst) {
    int z = blockIdx.y;
    const float* s = z == 0 ? s0 : z == 1 ? s1 : z == 2 ? s2 : z == 3 ? s3 : z == 4 ? s4 : z == 5 ? s5 : s6;
    unsigned short* d = dst + (size_t)z * 4194304;
    size_t i = ((size_t)blockIdx.x * 256 + threadIdx.x) * 8;
    float4 a = *(const float4*)(s + i);
    float4 b = *(const float4*)(s + i + 4);
    u16x8 o;
    o[0] = f2b(a.x); o[1] = f2b(a.y); o[2] = f2b(a.z); o[3] = f2b(a.w);
    o[4] = f2b(b.x); o[5] = f2b(b.y); o[6] = f2b(b.z); o[7] = f2b(b.w);
    *(u16x8*)(d + i) = o;
}

// ---------------- C = alpha * A(2048xK) @ B(2048xK)^T ----------------
// NT = n-tile (128 or 64). DO_VT: z==2 writes C^T to VT (row-major [n][m]) for the V projection.
template <int OUT_BF16, int NT, int DO_VT>
__global__ __launch_bounds__(256, 2) void gemm_bt(const unsigned short* __restrict__ Abase,
                                                  const unsigned short* __restrict__ Bbase,
                                                  void* __restrict__ Cbase,
                                                  unsigned short* __restrict__ VT,
                                                  float alpha0) {
    constexpr int MI = (NT == 128) ? 4 : 2;
    __shared__ __align__(16) unsigned short As[128 * 32];
    __shared__ __align__(16) unsigned short Bs[NT * 32];
    const int tid = threadIdx.x;
    const int w = tid >> 6, lane = tid & 63;
    const int quad = lane >> 4, l16 = lane & 15;
    const int b = blockIdx.z;
    const unsigned short* A = Abase + (size_t)b * 4194304;
    const unsigned short* B = Bbase + (size_t)b * 4194304;
    const float alpha = (b == 0) ? alpha0 : 1.0f;
    const int m0 = blockIdx.y * 128, n0 = blockIdx.x * NT;
    const int wm = (NT == 128) ? (w >> 1) * 64 : w * 32;
    const int wn = (NT == 128) ? (w & 1) * 64 : 0;
    const int sr = lane >> 2;                              // 0..15 row within 16-row slab
    const int sc = (((lane & 3) ^ ((lane >> 3) & 3)) * 8); // swizzled global colblock
    const int rsw = ((l16 >> 1) & 3);                      // read-side swizzle key

    f32x4 zz = {0.f, 0.f, 0.f, 0.f};
    f32x4 acc[MI][4];
#pragma unroll
    for (int i = 0; i < MI; ++i)
#pragma unroll
        for (int jn = 0; jn < 4; ++jn) acc[i][jn] = zz;

    for (int k0 = 0; k0 < 2048; k0 += 32) {
        GLD16(A + (size_t)(m0 + w * 16 + sr) * 2048 + k0 + sc,      &As[(w * 16) * 32]);
        GLD16(A + (size_t)(m0 + 64 + w * 16 + sr) * 2048 + k0 + sc, &As[(64 + w * 16) * 32]);
        if (NT == 128) {
            GLD16(B + (size_t)(n0 + w * 16 + sr) * 2048 + k0 + sc,      &Bs[(w * 16) * 32]);
            GLD16(B + (size_t)(n0 + 64 + w * 16 + sr) * 2048 + k0 + sc, &Bs[(64 + (w * 16)) * 32]);
        } else {
            GLD16(B + (size_t)(n0 + w * 16 + sr) * 2048 + k0 + sc, &Bs[(w * 16) * 32]);
        }
        __syncthreads();
        bf16x8 af[MI], bfr[4];
#pragma unroll
        for (int i = 0; i < MI; ++i) af[i]  = *(const bf16x8*)&As[(wm + i * 16 + l16) * 32 + (quad ^ rsw) * 8];
#pragma unroll
        for (int i = 0; i < 4; ++i)  bfr[i] = *(const bf16x8*)&Bs[(wn + i * 16 + l16) * 32 + (quad ^ rsw) * 8];
#pragma unroll
        for (int i = 0; i < MI; ++i)
#pragma unroll
            for (int jn = 0; jn < 4; ++jn)
                acc[i][jn] = __builtin_amdgcn_mfma_f32_16x16x32_bf16(af[i], bfr[jn], acc[i][jn], 0, 0, 0);
        __syncthreads();
    }

    if (DO_VT && b == 2) {
        // transposed write: VT[n][m], packed 4 bf16 (m-consecutive) per lane
#pragma unroll
        for (int i = 0; i < MI; ++i)
#pragma unroll
            for (int jn = 0; jn < 4; ++jn) {
                int n = n0 + wn + jn * 16 + l16;
                int m = m0 + wm + i * 16 + quad * 4;
                u16x4 o;
#pragma unroll
                for (int r = 0; r < 4; ++r) o[r] = f2b(acc[i][jn][r]);
                *(u16x4*)&VT[(size_t)n * 2048 + m] = o;
            }
    } else {
#pragma unroll
        for (int i = 0; i < MI; ++i)
#pragma unroll
            for (int jn = 0; jn < 4; ++jn)
#pragma unroll
                for (int r = 0; r < 4; ++r) {
                    int row = m0 + wm + i * 16 + quad * 4 + r;
                    int col = n0 + wn + jn * 16 + l16;
                    float v = acc[i][jn][r] * alpha;
                    if (OUT_BF16)
                        ((unsigned short*)Cbase + (size_t)b * 4194304)[(size_t)row * 2048 + col] = f2b(v);
                    else
                        ((float*)Cbase)[(size_t)row * 2048 + col] = v;
                }
    }
}

// ---------------- differential flash attention, S^T register path, KV chunk = 64 ----------------
// grid (32 qtiles, 16 head-pairs), 256 thr. Wave w owns 16 q-rows.
// LDS = Ks 16KB + Vs 16KB -> 4 blocks/CU (4 waves/SIMD). Q pre-scaled by HD^-0.5*log2e -> exp2.
__global__ __launch_bounds__(256, 4) void diff_attn(const unsigned short* __restrict__ qb,
                                                    const unsigned short* __restrict__ kb,
                                                    const unsigned short* __restrict__ vt,
                                                    const float* __restrict__ lq1,
                                                    const float* __restrict__ lk1,
                                                    const float* __restrict__ lq2,
                                                    const float* __restrict__ lk2,
                                                    const float* __restrict__ g,
                                                    unsigned short* __restrict__ Aout) {
    __shared__ __align__(16) unsigned short Ks[64 * 128];        // [kv][d], 16B-block ^ (kv&15) swizzle
    __shared__ __align__(16) unsigned short Vs[128 * 64];        // [d][kv], 16B-block ^ (d&7) swizzle
    __shared__ float lam_s;
    const int tid = threadIdx.x, w = tid >> 6, lane = tid & 63;
    const int quad = lane >> 4, l16 = lane & 15;
    const int j = blockIdx.y;
    const int q0 = blockIdx.x * 64;

    // lambda_full: wave 0 computes, published by the loop's first barrier
    if (tid < 64) {
        float p1 = lq1[tid] * lk1[tid];
        float p2 = lq2[tid] * lk2[tid];
        for (int off = 32; off; off >>= 1) { p1 += __shfl_xor(p1, off, 64); p2 += __shfl_xor(p2, off, 64); }
        if (tid == 0) lam_s = __expf(p1) - __expf(p2) + LAMBDA_INIT_F;
    }

    // Q as B-operand fragments: B[n=q=l16][k=d=quad*8+j]
    bf16x8 qf[2][2];
#pragma unroll
    for (int p = 0; p < 2; ++p)
#pragma unroll
        for (int dh = 0; dh < 2; ++dh)
            qf[p][dh] = *(const bf16x8*)&qb[(size_t)(q0 + w * 16 + l16) * 2048 + j * 128 + p * 64 + dh * 32 + quad * 8];

    f32x4 O[2][8];     // O^T accumulators: lane holds O^T[d=dt*16+quad*4+r][q=l16]
#pragma unroll
    for (int p = 0; p < 2; ++p)
#pragma unroll
        for (int i = 0; i < 8; ++i)
#pragma unroll
            for (int r = 0; r < 4; ++r) O[p][i][r] = 0.f;
    float lsum[2] = {0.f, 0.f};

    const int ksrow = lane >> 4;         // Ks staging: 4 rows per instr (256B rows)
    const int vsrow = lane >> 3;         // Vs staging: 8 rows per instr (128B rows)

    for (int kv0 = 0; kv0 < 2048; kv0 += 64) {
        // Ks: 64 rows x 256B = 16 instr; Vs: 128 rows x 128B = 16 instr; 8 per wave
#pragma unroll
        for (int t = 0; t < 4; ++t) {
            int krb = (w * 4 + t) * 4;           // Ks base row
            int krow = krb + ksrow;
            int kcb = (((lane & 15) ^ (krow & 15)) * 8);
            GLD16(kb + (size_t)(kv0 + krow) * 2048 + j * 128 + kcb, &Ks[krb * 128]);
            int vrb = (w * 4 + t) * 8;           // Vs base row (d)
            int vrow = vrb + vsrow;
            int vcb = (((lane & 7) ^ (vrow & 7)) * 8);
            GLD16(vt + (size_t)(j * 128 + vrow) * 2048 + kv0 + vcb, &Vs[vrb * 64]);
        }
        __syncthreads();

        s16x4 pf[2][4];   // exp2(S^T) bf16 B-fragments, per p per 16-kv tile
#pragma unroll
        for (int p = 0; p < 2; ++p) {
#pragma unroll
            for (int i = 0; i < 4; ++i) {
                // A = K fragment: A[m=kv=l16][k=d=quad*8+j] from Ks row i*16+l16
                bf16x8 a0 = *(const bf16x8*)&Ks[(i * 16 + l16) * 128 + ((p * 8 + quad) ^ l16) * 8];
                bf16x8 a1 = *(const bf16x8*)&Ks[(i * 16 + l16) * 128 + ((p * 8 + 4 + quad) ^ l16) * 8];
                f32x4 s = {0.f, 0.f, 0.f, 0.f};
                s = __builtin_amdgcn_mfma_f32_16x16x32_bf16(a0, qf[p][0], s, 0, 0, 0);
                s = __builtin_amdgcn_mfma_f32_16x16x32_bf16(a1, qf[p][1], s, 0, 0, 0);
                float e0 = EXP2(s[0]), e1 = EXP2(s[1]), e2 = EXP2(s[2]), e3 = EXP2(s[3]);
                lsum[p] += (e0 + e1) + (e2 + e3);
                unsigned d0 = pk2t(e0, e1), d1 = pk2t(e2, e3);
                s16x4 pv;
                pv[0] = (short)(d0 & 0xffff); pv[1] = (short)(d0 >> 16);
                pv[2] = (short)(d1 & 0xffff); pv[3] = (short)(d1 >> 16);
                pf[p][i] = pv;
            }
        }
        // PV: O^T[d][q] += V^T[d][kv] * P^T[kv][q]; V fragment shared across both p
#pragma unroll
        for (int i = 0; i < 4; ++i) {
#pragma unroll
            for (int dt = 0; dt < 8; ++dt) {
                int row = dt * 16 + l16;
                int blk = (i * 2 + (quad >> 1)) ^ (row & 7);   // 16B-block swizzle over 8 blocks
                s16x4 vf = *(const s16x4*)&Vs[row * 64 + blk * 8 + (quad & 1) * 4];
                O[0][dt] = __builtin_amdgcn_mfma_f32_16x16x16bf16_1k(vf, pf[0][i], O[0][dt], 0, 0, 0);
                O[1][dt] = __builtin_amdgcn_mfma_f32_16x16x16bf16_1k(vf, pf[1][i], O[1][dt], 0, 0, 0);
            }
        }
        __syncthreads();   // protect Ks/Vs before next chunk's staging
    }

    // row sums: each lane has partial over kv; reduce across quads (same l16 = same q)
#pragma unroll
    for (int p = 0; p < 2; ++p) {
        lsum[p] += __shfl_xor(lsum[p], 16, 64);
        lsum[p] += __shfl_xor(lsum[p], 32, 64);
    }
    const float inv1 = 1.0f / lsum[0];
    const float inv2 = lam_s / lsum[1];

    // diff + RMSNorm over d (across regs+quads for fixed q=l16)
    float ssum = 0.f;
#pragma unroll
    for (int dt = 0; dt < 8; ++dt)
#pragma unroll
        for (int r = 0; r < 4; ++r) {
            float v = O[0][dt][r] * inv1 - O[1][dt][r] * inv2;
            O[0][dt][r] = v;
            ssum += v * v;
        }
    ssum += __shfl_xor(ssum, 16, 64);
    ssum += __shfl_xor(ssum, 32, 64);
    const float rms = rsqrtf(ssum * (1.0f / 128.0f) + 1e-5f) * (1.0f - LAMBDA_INIT_F);

#pragma unroll
    for (int dt = 0; dt < 8; ++dt) {
        float4 g4 = *(const float4*)&g[dt * 16 + quad * 4];
        u16x4 o;
        o[0] = f2b(O[0][dt][0] * rms * g4.x);
        o[1] = f2b(O[0][dt][1] * rms * g4.y);
        o[2] = f2b(O[0][dt][2] * rms * g4.z);
        o[3] = f2b(O[0][dt][3] * rms * g4.w);
        *(u16x4*)&Aout[(size_t)(q0 + w * 16 + l16) * 2048 + j * 128 + dt * 16 + quad * 4] = o;
    }
}

extern "C" void kernel_launch(void* const* d_in, const int* in_sizes, int n_in,
                              void* d_out, int out_size, void* d_ws, size_t ws_size,
                              hipStream_t stream) {
    const float* query = (const float*)d_in[0];
    const float* key   = (const float*)d_in[1];
    const float* value = (const float*)d_in[2];
    const float* Wq  = (const float*)d_in[5];
    const float* Wk  = (const float*)d_in[6];
    const float* Wv  = (const float*)d_in[7];
    const float* Wo  = (const float*)d_in[8];
    const float* lq1 = (const float*)d_in[9];
    const float* lk1 = (const float*)d_in[10];
    const float* lq2 = (const float*)d_in[11];
    const float* lk2 = (const float*)d_in[12];
    const float* g   = (const float*)d_in[13];

    char* ws = (char*)d_ws;
    const size_t MB = 1ull << 20;
    const size_t N4 = 4194304;  // 2048*2048
    unsigned short* qb  = (unsigned short*)(ws + 0 * MB);    // qb,kb contiguous (batched GEMM out z=0,1)
    unsigned short* vt  = (unsigned short*)(ws + 16 * MB);   // V^T (z=2 transposed epilogue)
    unsigned short* Aat = (unsigned short*)(ws + 24 * MB);
    unsigned short* Xq  = (unsigned short*)(ws + 32 * MB);   // Xq,Xk,Xv then Wq,Wk,Wv,Wo: 7 contiguous slabs

    // alpha = HD^-0.5 * log2(e): scores come out in log2 domain -> raw v_exp_f32 in diff_attn
    const float alpha_q = 0.125f * 1.44269504f;

    cvt7<<<dim3(2048, 7), dim3(256), 0, stream>>>(query, key, value, Wq, Wk, Wv, Wo, Xq);
    // q/k/v projections (z batches 3 GEMMs); z=2 -> vt transposed
    gemm_bt<1, 128, 1><<<dim3(16, 16, 3), dim3(256), 0, stream>>>(Xq, Xq + 3 * N4, (void*)qb, vt, alpha_q);
    diff_attn<<<dim3(32, 16), dim3(256), 0, stream>>>(qb, qb + N4, vt, lq1, lk1, lq2, lk2, g, Aat);
    // output projection: 128x128 tiles -> 256 blocks, m97-class ratio
    gemm_bt<0, 128, 0><<<dim3(16, 16, 1), dim3(256), 0, stream>>>(Aat, Xq + 6 * N4, d_out, nullptr, 1.0f);
}

// Round 6
// 352.235 us; speedup vs baseline: 1.1546x; 1.1546x over previous
//
#include <hip/hip_runtime.h>
#include <stdint.h>

#define LAMBDA_INIT_F 0.7836057665f   // 0.8 - 0.6*exp(-0.3*12)

typedef __bf16 bf16x8 __attribute__((ext_vector_type(8)));
typedef float  f32x4  __attribute__((ext_vector_type(4)));
typedef unsigned short u16x8 __attribute__((ext_vector_type(8)));
typedef unsigned short u16x4 __attribute__((ext_vector_type(4)));
typedef short s16x4 __attribute__((ext_vector_type(4)));

__device__ __forceinline__ unsigned short f2b(float f) {
    union { float f; unsigned u; } v; v.f = f;
    unsigned u = v.u;
    return (unsigned short)((u + 0x7fffu + ((u >> 16) & 1u)) >> 16);
}

// pack two fp32 -> two bf16 (truncate) in one dword — P-only, bias cancels in softmax ratio
__device__ __forceinline__ unsigned pk2t(float a, float b) {
    return __builtin_amdgcn_perm(__float_as_uint(b), __float_as_uint(a), 0x07060302u);
}

#if __has_builtin(__builtin_amdgcn_exp2f)
#define EXP2(x) __builtin_amdgcn_exp2f(x)
#else
__device__ __forceinline__ float EXP2(float x) {
    float r; asm volatile("v_exp_f32 %0, %1\n\ts_nop 1" : "=v"(r) : "v"(x)); return r;
}
#endif

// global(16B/lane) -> LDS direct. LDS base must be wave-uniform; lanes land at base + lane*16.
#define GLD16(gp, sp) __builtin_amdgcn_global_load_lds( \
    (const __attribute__((address_space(1))) void*)(uintptr_t)(gp), \
    (__attribute__((address_space(3))) void*)(uint32_t)(uintptr_t)(sp), 16, 0, 0)

// ---------------- fp32 -> bf16 convert, 7 slabs of 4M elements ----------------
__global__ __launch_bounds__(256) void cvt7(const float* __restrict__ s0, const float* __restrict__ s1,
                                            const float* __restrict__ s2, const float* __restrict__ s3,
                                            const float* __restrict__ s4, const float* __restrict__ s5,
                                            const float* __restrict__ s6,
                                            unsigned short* __restrict__ dst) {
    int z = blockIdx.y;
    const float* s = z == 0 ? s0 : z == 1 ? s1 : z == 2 ? s2 : z == 3 ? s3 : z == 4 ? s4 : z == 5 ? s5 : s6;
    unsigned short* d = dst + (size_t)z * 4194304;
    size_t i = ((size_t)blockIdx.x * 256 + threadIdx.x) * 8;
    float4 a = *(const float4*)(s + i);
    float4 b = *(const float4*)(s + i + 4);
    u16x8 o;
    o[0] = f2b(a.x); o[1] = f2b(a.y); o[2] = f2b(a.z); o[3] = f2b(a.w);
    o[4] = f2b(b.x); o[5] = f2b(b.y); o[6] = f2b(b.z); o[7] = f2b(b.w);
    *(u16x8*)(d + i) = o;
}

// ---------------- C = alpha * A(128-tile) @ B(2048xK)^T, BK=64 (half the barriers of m97) ----------
// PROJ=1: blockIdx.z selects 4M-elem slab triple; bf16 out; z==2 writes C^T to VT.
// PROJ=0: split-K — blockIdx.z selects K-half [z*1024,(z+1)*1024); fp32 atomicAdd into Cbase.
// Note (gfx950 unified RF): VGPR+AGPR must fit 256/wave -> WPB=2 only.
template <int PROJ>
__global__ __launch_bounds__(256, 2) void gemm_bt(const unsigned short* __restrict__ Abase,
                                                  const unsigned short* __restrict__ Bbase,
                                                  void* __restrict__ Cbase,
                                                  unsigned short* __restrict__ VT,
                                                  float alpha0) {
    __shared__ __align__(16) unsigned short As[128 * 64];
    __shared__ __align__(16) unsigned short Bs[128 * 64];
    const int tid = threadIdx.x;
    const int w = tid >> 6, lane = tid & 63;
    const int quad = lane >> 4, l16 = lane & 15;
    const int b = blockIdx.z;
    const unsigned short* A = PROJ ? Abase + (size_t)b * 4194304 : Abase;
    const unsigned short* B = PROJ ? Bbase + (size_t)b * 4194304 : Bbase;
    const int kbeg = PROJ ? 0 : b * 1024;
    const int kend = PROJ ? 2048 : (b * 1024 + 1024);
    const float alpha = (PROJ && b != 0) ? 1.0f : alpha0;
    const int m0 = blockIdx.y * 128, n0 = blockIdx.x * 128;
    const int wm = (w >> 1) * 64, wn = (w & 1) * 64;
    const int sr8 = lane >> 3;          // 0..7: row within an 8-row staging slab (128B rows)
    const int sblk = lane & 7;          // 16B block within the row
    const int rk = l16 & 7;             // read-side swizzle key

    f32x4 zz = {0.f, 0.f, 0.f, 0.f};
    f32x4 acc[4][4];
#pragma unroll
    for (int i = 0; i < 4; ++i)
#pragma unroll
        for (int jn = 0; jn < 4; ++jn) acc[i][jn] = zz;

    for (int k0 = kbeg; k0 < kend; k0 += 64) {
#pragma unroll
        for (int t = 0; t < 4; ++t) {
            int rb = w * 32 + t * 8;
            int ra = rb + sr8;
            int ca = (sblk ^ (ra & 7)) * 8;   // swizzled source colblock (stays in row's 128B)
            GLD16(A + (size_t)(m0 + ra) * 2048 + k0 + ca, &As[rb * 64]);
            GLD16(B + (size_t)(n0 + ra) * 2048 + k0 + ca, &Bs[rb * 64]);
        }
        __syncthreads();
#pragma unroll
        for (int ks = 0; ks < 2; ++ks) {     // two K=32 sub-steps, registers reused
            bf16x8 af[4], bfr[4];
#pragma unroll
            for (int i = 0; i < 4; ++i)
                af[i]  = *(const bf16x8*)&As[(wm + i * 16 + l16) * 64 + ((ks * 4 + quad) ^ rk) * 8];
#pragma unroll
            for (int i = 0; i < 4; ++i)
                bfr[i] = *(const bf16x8*)&Bs[(wn + i * 16 + l16) * 64 + ((ks * 4 + quad) ^ rk) * 8];
#pragma unroll
            for (int i = 0; i < 4; ++i)
#pragma unroll
                for (int jn = 0; jn < 4; ++jn)
                    acc[i][jn] = __builtin_amdgcn_mfma_f32_16x16x32_bf16(af[i], bfr[jn], acc[i][jn], 0, 0, 0);
        }
        __syncthreads();
    }

    if (PROJ) {
        if (b == 2) {
            // transposed write: VT[n][m], packed 4 bf16 (m-consecutive) per lane
#pragma unroll
            for (int i = 0; i < 4; ++i)
#pragma unroll
                for (int jn = 0; jn < 4; ++jn) {
                    int n = n0 + wn + jn * 16 + l16;
                    int m = m0 + wm + i * 16 + quad * 4;
                    u16x4 o;
#pragma unroll
                    for (int r = 0; r < 4; ++r) o[r] = f2b(acc[i][jn][r]);
                    *(u16x4*)&VT[(size_t)n * 2048 + m] = o;
                }
        } else {
#pragma unroll
            for (int i = 0; i < 4; ++i)
#pragma unroll
                for (int jn = 0; jn < 4; ++jn)
#pragma unroll
                    for (int r = 0; r < 4; ++r) {
                        int row = m0 + wm + i * 16 + quad * 4 + r;
                        int col = n0 + wn + jn * 16 + l16;
                        ((unsigned short*)Cbase + (size_t)b * 4194304)[(size_t)row * 2048 + col] =
                            f2b(acc[i][jn][r] * alpha);
                    }
        }
    } else {
        // split-K: accumulate into zero-initialized fp32 output
#pragma unroll
        for (int i = 0; i < 4; ++i)
#pragma unroll
            for (int jn = 0; jn < 4; ++jn)
#pragma unroll
                for (int r = 0; r < 4; ++r) {
                    int row = m0 + wm + i * 16 + quad * 4 + r;
                    int col = n0 + wn + jn * 16 + l16;
                    atomicAdd(&((float*)Cbase)[(size_t)row * 2048 + col], acc[i][jn][r]);
                }
    }
}

// ---------------- differential flash attention, S^T register path (R4 winner) ----------------
// grid (32 qtiles, 16 head-pairs), 256 thr. Wave w owns 16 q-rows; KV chunks of 128.
// Q pre-scaled by HD^-0.5*log2e -> raw exp2. WPB=2: unified RF needs 128 VGPR + 64 acc = 192 <= 256.
__global__ __launch_bounds__(256, 2) void diff_attn(const unsigned short* __restrict__ qb,
                                                    const unsigned short* __restrict__ kb,
                                                    const unsigned short* __restrict__ vt,
                                                    const float* __restrict__ lq1,
                                                    const float* __restrict__ lk1,
                                                    const float* __restrict__ lq2,
                                                    const float* __restrict__ lk2,
                                                    const float* __restrict__ g,
                                                    unsigned short* __restrict__ Aout) {
    __shared__ __align__(16) unsigned short Ks[128 * 128];       // [kv][d], 16B-block ^ (kv&15) swizzle
    __shared__ __align__(16) unsigned short Vs[128 * 128];       // [d][kv], same swizzle
    __shared__ float lam_s;
    const int tid = threadIdx.x, w = tid >> 6, lane = tid & 63;
    const int quad = lane >> 4, l16 = lane & 15;
    const int j = blockIdx.y;
    const int q0 = blockIdx.x * 64;

    // lambda_full: wave 0 computes, published by the loop's first barrier
    if (tid < 64) {
        float p1 = lq1[tid] * lk1[tid];
        float p2 = lq2[tid] * lk2[tid];
        for (int off = 32; off; off >>= 1) { p1 += __shfl_xor(p1, off, 64); p2 += __shfl_xor(p2, off, 64); }
        if (tid == 0) lam_s = __expf(p1) - __expf(p2) + LAMBDA_INIT_F;
    }

    // Q as B-operand fragments: B[n=q=l16][k=d=quad*8+j]
    bf16x8 qf[2][2];
#pragma unroll
    for (int p = 0; p < 2; ++p)
#pragma unroll
        for (int dh = 0; dh < 2; ++dh)
            qf[p][dh] = *(const bf16x8*)&qb[(size_t)(q0 + w * 16 + l16) * 2048 + j * 128 + p * 64 + dh * 32 + quad * 8];

    f32x4 O[2][8];     // O^T accumulators: lane holds O^T[d=dt*16+quad*4+r][q=l16]
#pragma unroll
    for (int p = 0; p < 2; ++p)
#pragma unroll
        for (int i = 0; i < 8; ++i)
#pragma unroll
            for (int r = 0; r < 4; ++r) O[p][i][r] = 0.f;
    float lsum[2] = {0.f, 0.f};

    const int srow = lane >> 4;          // 0..3 (4 rows of 256B per staging instr)

    for (int kv0 = 0; kv0 < 2048; kv0 += 128) {
#pragma unroll
        for (int t = 0; t < 8; ++t) {
            int rb = (w * 8 + t) * 4;
            int row = rb + srow;
            int cbs = (((lane & 15) ^ (row & 15)) * 8);   // swizzled global colblock
            GLD16(kb + (size_t)(kv0 + row) * 2048 + j * 128 + cbs, &Ks[rb * 128]);
            GLD16(vt + (size_t)(j * 128 + row) * 2048 + kv0 + cbs, &Vs[rb * 128]);
        }
        __syncthreads();

        s16x4 pf[2][8];   // exp2(S^T) bf16 B-fragments, per p per 16-kv tile
#pragma unroll
        for (int p = 0; p < 2; ++p) {
#pragma unroll
            for (int i = 0; i < 8; ++i) {
                // A = K fragment: A[m=kv=l16][k=d=quad*8+j] from Ks row i*16+l16
                bf16x8 a0 = *(const bf16x8*)&Ks[(i * 16 + l16) * 128 + ((p * 8 + quad) ^ l16) * 8];
                bf16x8 a1 = *(const bf16x8*)&Ks[(i * 16 + l16) * 128 + ((p * 8 + 4 + quad) ^ l16) * 8];
                f32x4 s = {0.f, 0.f, 0.f, 0.f};
                s = __builtin_amdgcn_mfma_f32_16x16x32_bf16(a0, qf[p][0], s, 0, 0, 0);
                s = __builtin_amdgcn_mfma_f32_16x16x32_bf16(a1, qf[p][1], s, 0, 0, 0);
                float e0 = EXP2(s[0]), e1 = EXP2(s[1]), e2 = EXP2(s[2]), e3 = EXP2(s[3]);
                lsum[p] += (e0 + e1) + (e2 + e3);
                unsigned d0 = pk2t(e0, e1), d1 = pk2t(e2, e3);
                s16x4 pv;
                pv[0] = (short)(d0 & 0xffff); pv[1] = (short)(d0 >> 16);
                pv[2] = (short)(d1 & 0xffff); pv[3] = (short)(d1 >> 16);
                pf[p][i] = pv;
            }
        }
        // PV: O^T[d][q] += V^T[d][kv] * P^T[kv][q]; V fragment shared across both p
#pragma unroll
        for (int i = 0; i < 8; ++i) {
#pragma unroll
            for (int dt = 0; dt < 8; ++dt) {
                int blk = (i * 2 + (quad >> 1)) ^ l16;    // 16B-block swizzle, row&15 = l16
                s16x4 vf = *(const s16x4*)&Vs[(dt * 16 + l16) * 128 + blk * 8 + (quad & 1) * 4];
                O[0][dt] = __builtin_amdgcn_mfma_f32_16x16x16bf16_1k(vf, pf[0][i], O[0][dt], 0, 0, 0);
                O[1][dt] = __builtin_amdgcn_mfma_f32_16x16x16bf16_1k(vf, pf[1][i], O[1][dt], 0, 0, 0);
            }
        }
        __syncthreads();   // protect Ks/Vs before next chunk's staging
    }

    // row sums: reduce across quads (same l16 = same q)
#pragma unroll
    for (int p = 0; p < 2; ++p) {
        lsum[p] += __shfl_xor(lsum[p], 16, 64);
        lsum[p] += __shfl_xor(lsum[p], 32, 64);
    }
    const float inv1 = 1.0f / lsum[0];
    const float inv2 = lam_s / lsum[1];

    // diff + RMSNorm over d (across regs+quads for fixed q=l16)
    float ssum = 0.f;
#pragma unroll
    for (int dt = 0; dt < 8; ++dt)
#pragma unroll
        for (int r = 0; r < 4; ++r) {
            float v = O[0][dt][r] * inv1 - O[1][dt][r] * inv2;
            O[0][dt][r] = v;
            ssum += v * v;
        }
    ssum += __shfl_xor(ssum, 16, 64);
    ssum += __shfl_xor(ssum, 32, 64);
    const float rms = rsqrtf(ssum * (1.0f / 128.0f) + 1e-5f) * (1.0f - LAMBDA_INIT_F);

#pragma unroll
    for (int dt = 0; dt < 8; ++dt) {
        float4 g4 = *(const float4*)&g[dt * 16 + quad * 4];
        u16x4 o;
        o[0] = f2b(O[0][dt][0] * rms * g4.x);
        o[1] = f2b(O[0][dt][1] * rms * g4.y);
        o[2] = f2b(O[0][dt][2] * rms * g4.z);
        o[3] = f2b(O[0][dt][3] * rms * g4.w);
        *(u16x4*)&Aout[(size_t)(q0 + w * 16 + l16) * 2048 + j * 128 + dt * 16 + quad * 4] = o;
    }
}

extern "C" void kernel_launch(void* const* d_in, const int* in_sizes, int n_in,
                              void* d_out, int out_size, void* d_ws, size_t ws_size,
                              hipStream_t stream) {
    const float* query = (const float*)d_in[0];
    const float* key   = (const float*)d_in[1];
    const float* value = (const float*)d_in[2];
    const float* Wq  = (const float*)d_in[5];
    const float* Wk  = (const float*)d_in[6];
    const float* Wv  = (const float*)d_in[7];
    const float* Wo  = (const float*)d_in[8];
    const float* lq1 = (const float*)d_in[9];
    const float* lk1 = (const float*)d_in[10];
    const float* lq2 = (const float*)d_in[11];
    const float* lk2 = (const float*)d_in[12];
    const float* g   = (const float*)d_in[13];

    char* ws = (char*)d_ws;
    const size_t MB = 1ull << 20;
    const size_t N4 = 4194304;  // 2048*2048
    unsigned short* qb  = (unsigned short*)(ws + 0 * MB);    // qb,kb contiguous (batched GEMM out z=0,1)
    unsigned short* vt  = (unsigned short*)(ws + 16 * MB);   // V^T (z=2 transposed epilogue)
    unsigned short* Aat = (unsigned short*)(ws + 24 * MB);
    unsigned short* Xq  = (unsigned short*)(ws + 32 * MB);   // Xq,Xk,Xv then Wq,Wk,Wv,Wo: 7 contiguous slabs

    // alpha = HD^-0.5 * log2(e): scores come out in log2 domain -> raw v_exp_f32 in diff_attn
    const float alpha_q = 0.125f * 1.44269504f;

    cvt7<<<dim3(2048, 7), dim3(256), 0, stream>>>(query, key, value, Wq, Wk, Wv, Wo, Xq);
    // q/k/v projections (z batches 3 GEMMs); z=2 -> vt transposed
    gemm_bt<1><<<dim3(16, 16, 3), dim3(256), 0, stream>>>(Xq, Xq + 3 * N4, (void*)qb, vt, alpha_q);
    diff_attn<<<dim3(32, 16), dim3(256), 0, stream>>>(qb, qb + N4, vt, lq1, lk1, lq2, lk2, g, Aat);
    // output projection: split-K x2 (512 blocks, full residency), fp32 atomic accumulate
    hipMemsetAsync(d_out, 0, (size_t)out_size * sizeof(float), stream);
    gemm_bt<0><<<dim3(16, 16, 2), dim3(256), 0, stream>>>(Aat, Xq + 6 * N4, d_out, nullptr, 1.0f);
}

// Round 7
// 338.614 us; speedup vs baseline: 1.2010x; 1.0402x over previous
//
#include <hip/hip_runtime.h>
#include <stdint.h>

#define LAMBDA_INIT_F 0.7836057665f   // 0.8 - 0.6*exp(-0.3*12)

typedef __bf16 bf16x8 __attribute__((ext_vector_type(8)));
typedef float  f32x4  __attribute__((ext_vector_type(4)));
typedef unsigned short u16x8 __attribute__((ext_vector_type(8)));
typedef unsigned short u16x4 __attribute__((ext_vector_type(4)));
typedef short s16x4 __attribute__((ext_vector_type(4)));

__device__ __forceinline__ unsigned short f2b(float f) {
    union { float f; unsigned u; } v; v.f = f;
    unsigned u = v.u;
    return (unsigned short)((u + 0x7fffu + ((u >> 16) & 1u)) >> 16);
}

// pack two fp32 -> two bf16 (truncate) in one dword — P-only, bias cancels in softmax ratio
__device__ __forceinline__ unsigned pk2t(float a, float b) {
    return __builtin_amdgcn_perm(__float_as_uint(b), __float_as_uint(a), 0x07060302u);
}

#if __has_builtin(__builtin_amdgcn_exp2f)
#define EXP2(x) __builtin_amdgcn_exp2f(x)
#else
__device__ __forceinline__ float EXP2(float x) {
    float r; asm volatile("v_exp_f32 %0, %1\n\ts_nop 1" : "=v"(r) : "v"(x)); return r;
}
#endif

// global(16B/lane) -> LDS direct. LDS base must be wave-uniform; lanes land at base + lane*16.
#define GLD16(gp, sp) __builtin_amdgcn_global_load_lds( \
    (const __attribute__((address_space(1))) void*)(uintptr_t)(gp), \
    (__attribute__((address_space(3))) void*)(uint32_t)(uintptr_t)(sp), 16, 0, 0)

// ---------------- fp32 -> bf16 convert, 7 slabs of 4M elements ----------------
__global__ __launch_bounds__(256) void cvt7(const float* __restrict__ s0, const float* __restrict__ s1,
                                            const float* __restrict__ s2, const float* __restrict__ s3,
                                            const float* __restrict__ s4, const float* __restrict__ s5,
                                            const float* __restrict__ s6,
                                            unsigned short* __restrict__ dst) {
    int z = blockIdx.y;
    const float* s = z == 0 ? s0 : z == 1 ? s1 : z == 2 ? s2 : z == 3 ? s3 : z == 4 ? s4 : z == 5 ? s5 : s6;
    unsigned short* d = dst + (size_t)z * 4194304;
    size_t i = ((size_t)blockIdx.x * 256 + threadIdx.x) * 8;
    float4 a = *(const float4*)(s + i);
    float4 b = *(const float4*)(s + i + 4);
    u16x8 o;
    o[0] = f2b(a.x); o[1] = f2b(a.y); o[2] = f2b(a.z); o[3] = f2b(a.w);
    o[4] = f2b(b.x); o[5] = f2b(b.y); o[6] = f2b(b.z); o[7] = f2b(b.w);
    *(u16x8*)(d + i) = o;
}

// ---------------- q/k/v projection GEMM: 2-wave blocks, 128x128 tile, single-pass 3 blocks/CU ----
// 128 threads = 2 waves; wave w computes 64m x 128n (acc[4][8] = 128 acc regs; total ~200 <= 256
// unified-RF cap at 2 waves/SIMD). 768 blocks -> 3/CU balanced, zero tail.
// z = blockIdx.z selects (X,W) slab pair; z==2 writes C^T to VT.
__global__ __launch_bounds__(128, 2) void gemm_proj(const unsigned short* __restrict__ Xb,
                                                    const unsigned short* __restrict__ Wb,
                                                    unsigned short* __restrict__ Cb,
                                                    unsigned short* __restrict__ VT,
                                                    float alpha0) {
    __shared__ __align__(16) unsigned short As[128 * 32];
    __shared__ __align__(16) unsigned short Bs[128 * 32];
    const int tid = threadIdx.x;
    const int w = tid >> 6, lane = tid & 63;
    const int quad = lane >> 4, l16 = lane & 15;
    const int z = blockIdx.z;
    const unsigned short* A = Xb + (size_t)z * 4194304;
    const unsigned short* B = Wb + (size_t)z * 4194304;
    const float alpha = (z == 0) ? alpha0 : 1.0f;
    const int m0 = blockIdx.y * 128, n0 = blockIdx.x * 128;
    const int wm = w * 64;
    const int sr = lane >> 2;                              // 0..15 row within 16-row slab
    const int sc = (((lane & 3) ^ ((lane >> 3) & 3)) * 8); // swizzled global colblock
    const int rsw = ((l16 >> 1) & 3);                      // read-side swizzle key

    f32x4 zz = {0.f, 0.f, 0.f, 0.f};
    f32x4 acc[4][8];
#pragma unroll
    for (int i = 0; i < 4; ++i)
#pragma unroll
        for (int jn = 0; jn < 8; ++jn) acc[i][jn] = zz;

    for (int k0 = 0; k0 < 2048; k0 += 32) {
        // wave w stages A rows [w*64, w*64+64) and B rows same: 4+4 GLD16
#pragma unroll
        for (int t = 0; t < 4; ++t) {
            int rb = w * 64 + t * 16;
            GLD16(A + (size_t)(m0 + rb + sr) * 2048 + k0 + sc, &As[rb * 32]);
            GLD16(B + (size_t)(n0 + rb + sr) * 2048 + k0 + sc, &Bs[rb * 32]);
        }
        __syncthreads();
        bf16x8 af[4];
#pragma unroll
        for (int i = 0; i < 4; ++i)
            af[i] = *(const bf16x8*)&As[(wm + i * 16 + l16) * 32 + (quad ^ rsw) * 8];
#pragma unroll
        for (int jn = 0; jn < 8; ++jn) {
            bf16x8 bfr = *(const bf16x8*)&Bs[(jn * 16 + l16) * 32 + (quad ^ rsw) * 8];
#pragma unroll
            for (int i = 0; i < 4; ++i)
                acc[i][jn] = __builtin_amdgcn_mfma_f32_16x16x32_bf16(af[i], bfr, acc[i][jn], 0, 0, 0);
        }
        __syncthreads();
    }

    if (z == 2) {
        // transposed write: VT[n][m], packed 4 bf16 (m-consecutive) per lane
#pragma unroll
        for (int i = 0; i < 4; ++i)
#pragma unroll
            for (int jn = 0; jn < 8; ++jn) {
                int n = n0 + jn * 16 + l16;
                int m = m0 + wm + i * 16 + quad * 4;
                u16x4 o;
#pragma unroll
                for (int r = 0; r < 4; ++r) o[r] = f2b(acc[i][jn][r]);
                *(u16x4*)&VT[(size_t)n * 2048 + m] = o;
            }
    } else {
        unsigned short* C = Cb + (size_t)z * 4194304;
#pragma unroll
        for (int i = 0; i < 4; ++i)
#pragma unroll
            for (int jn = 0; jn < 8; ++jn)
#pragma unroll
                for (int r = 0; r < 4; ++r) {
                    int row = m0 + wm + i * 16 + quad * 4 + r;
                    int col = n0 + jn * 16 + l16;
                    C[(size_t)row * 2048 + col] = f2b(acc[i][jn][r] * alpha);
                }
    }
}

// ---------------- output projection: 128x64 tiles, full K, fp32 out (R3 winner) ----------------
__global__ __launch_bounds__(256, 2) void gemm_out(const unsigned short* __restrict__ A,
                                                   const unsigned short* __restrict__ B,
                                                   float* __restrict__ C) {
    __shared__ __align__(16) unsigned short As[128 * 32];
    __shared__ __align__(16) unsigned short Bs[64 * 32];
    const int tid = threadIdx.x;
    const int w = tid >> 6, lane = tid & 63;
    const int quad = lane >> 4, l16 = lane & 15;
    const int m0 = blockIdx.y * 128, n0 = blockIdx.x * 64;
    const int wm = w * 32;
    const int sr = lane >> 2;
    const int sc = (((lane & 3) ^ ((lane >> 3) & 3)) * 8);
    const int rsw = ((l16 >> 1) & 3);

    f32x4 zz = {0.f, 0.f, 0.f, 0.f};
    f32x4 acc[2][4];
#pragma unroll
    for (int i = 0; i < 2; ++i)
#pragma unroll
        for (int jn = 0; jn < 4; ++jn) acc[i][jn] = zz;

    for (int k0 = 0; k0 < 2048; k0 += 32) {
        GLD16(A + (size_t)(m0 + w * 16 + sr) * 2048 + k0 + sc,      &As[(w * 16) * 32]);
        GLD16(A + (size_t)(m0 + 64 + w * 16 + sr) * 2048 + k0 + sc, &As[(64 + w * 16) * 32]);
        GLD16(B + (size_t)(n0 + w * 16 + sr) * 2048 + k0 + sc,      &Bs[(w * 16) * 32]);
        __syncthreads();
        bf16x8 af[2], bfr[4];
#pragma unroll
        for (int i = 0; i < 2; ++i) af[i]  = *(const bf16x8*)&As[(wm + i * 16 + l16) * 32 + (quad ^ rsw) * 8];
#pragma unroll
        for (int i = 0; i < 4; ++i)  bfr[i] = *(const bf16x8*)&Bs[(i * 16 + l16) * 32 + (quad ^ rsw) * 8];
#pragma unroll
        for (int i = 0; i < 2; ++i)
#pragma unroll
            for (int jn = 0; jn < 4; ++jn)
                acc[i][jn] = __builtin_amdgcn_mfma_f32_16x16x32_bf16(af[i], bfr[jn], acc[i][jn], 0, 0, 0);
        __syncthreads();
    }

#pragma unroll
    for (int i = 0; i < 2; ++i)
#pragma unroll
        for (int jn = 0; jn < 4; ++jn)
#pragma unroll
            for (int r = 0; r < 4; ++r) {
                int row = m0 + wm + i * 16 + quad * 4 + r;
                int col = n0 + jn * 16 + l16;
                C[(size_t)row * 2048 + col] = acc[i][jn][r];
            }
}

// ---------------- differential flash attention, S^T register path (R4/R6 winner) ----------------
// grid (32 qtiles, 16 head-pairs), 256 thr. Wave w owns 16 q-rows; KV chunks of 128.
// Q pre-scaled by HD^-0.5*log2e -> raw exp2. WPB=2: unified RF 124 VGPR + 64 acc <= 256.
__global__ __launch_bounds__(256, 2) void diff_attn(const unsigned short* __restrict__ qb,
                                                    const unsigned short* __restrict__ kb,
                                                    const unsigned short* __restrict__ vt,
                                                    const float* __restrict__ lq1,
                                                    const float* __restrict__ lk1,
                                                    const float* __restrict__ lq2,
                                                    const float* __restrict__ lk2,
                                                    const float* __restrict__ g,
                                                    unsigned short* __restrict__ Aout) {
    __shared__ __align__(16) unsigned short Ks[128 * 128];       // [kv][d], 16B-block ^ (kv&15) swizzle
    __shared__ __align__(16) unsigned short Vs[128 * 128];       // [d][kv], same swizzle
    __shared__ float lam_s;
    const int tid = threadIdx.x, w = tid >> 6, lane = tid & 63;
    const int quad = lane >> 4, l16 = lane & 15;
    const int j = blockIdx.y;
    const int q0 = blockIdx.x * 64;

    // lambda_full: wave 0 computes, published by the loop's first barrier
    if (tid < 64) {
        float p1 = lq1[tid] * lk1[tid];
        float p2 = lq2[tid] * lk2[tid];
        for (int off = 32; off; off >>= 1) { p1 += __shfl_xor(p1, off, 64); p2 += __shfl_xor(p2, off, 64); }
        if (tid == 0) lam_s = __expf(p1) - __expf(p2) + LAMBDA_INIT_F;
    }

    // Q as B-operand fragments: B[n=q=l16][k=d=quad*8+j]
    bf16x8 qf[2][2];
#pragma unroll
    for (int p = 0; p < 2; ++p)
#pragma unroll
        for (int dh = 0; dh < 2; ++dh)
            qf[p][dh] = *(const bf16x8*)&qb[(size_t)(q0 + w * 16 + l16) * 2048 + j * 128 + p * 64 + dh * 32 + quad * 8];

    f32x4 O[2][8];     // O^T accumulators: lane holds O^T[d=dt*16+quad*4+r][q=l16]
#pragma unroll
    for (int p = 0; p < 2; ++p)
#pragma unroll
        for (int i = 0; i < 8; ++i)
#pragma unroll
            for (int r = 0; r < 4; ++r) O[p][i][r] = 0.f;
    float lsum[2] = {0.f, 0.f};

    const int srow = lane >> 4;          // 0..3 (4 rows of 256B per staging instr)

    for (int kv0 = 0; kv0 < 2048; kv0 += 128) {
#pragma unroll
        for (int t = 0; t < 8; ++t) {
            int rb = (w * 8 + t) * 4;
            int row = rb + srow;
            int cbs = (((lane & 15) ^ (row & 15)) * 8);   // swizzled global colblock
            GLD16(kb + (size_t)(kv0 + row) * 2048 + j * 128 + cbs, &Ks[rb * 128]);
            GLD16(vt + (size_t)(j * 128 + row) * 2048 + kv0 + cbs, &Vs[rb * 128]);
        }
        __syncthreads();

        s16x4 pf[2][8];   // exp2(S^T) bf16 B-fragments, per p per 16-kv tile
#pragma unroll
        for (int p = 0; p < 2; ++p) {
#pragma unroll
            for (int i = 0; i < 8; ++i) {
                // A = K fragment: A[m=kv=l16][k=d=quad*8+j] from Ks row i*16+l16
                bf16x8 a0 = *(const bf16x8*)&Ks[(i * 16 + l16) * 128 + ((p * 8 + quad) ^ l16) * 8];
                bf16x8 a1 = *(const bf16x8*)&Ks[(i * 16 + l16) * 128 + ((p * 8 + 4 + quad) ^ l16) * 8];
                f32x4 s = {0.f, 0.f, 0.f, 0.f};
                s = __builtin_amdgcn_mfma_f32_16x16x32_bf16(a0, qf[p][0], s, 0, 0, 0);
                s = __builtin_amdgcn_mfma_f32_16x16x32_bf16(a1, qf[p][1], s, 0, 0, 0);
                float e0 = EXP2(s[0]), e1 = EXP2(s[1]), e2 = EXP2(s[2]), e3 = EXP2(s[3]);
                lsum[p] += (e0 + e1) + (e2 + e3);
                unsigned d0 = pk2t(e0, e1), d1 = pk2t(e2, e3);
                s16x4 pv;
                pv[0] = (short)(d0 & 0xffff); pv[1] = (short)(d0 >> 16);
                pv[2] = (short)(d1 & 0xffff); pv[3] = (short)(d1 >> 16);
                pf[p][i] = pv;
            }
        }
        // PV: O^T[d][q] += V^T[d][kv] * P^T[kv][q]; V fragment shared across both p
#pragma unroll
        for (int i = 0; i < 8; ++i) {
#pragma unroll
            for (int dt = 0; dt < 8; ++dt) {
                int blk = (i * 2 + (quad >> 1)) ^ l16;    // 16B-block swizzle, row&15 = l16
                s16x4 vf = *(const s16x4*)&Vs[(dt * 16 + l16) * 128 + blk * 8 + (quad & 1) * 4];
                O[0][dt] = __builtin_amdgcn_mfma_f32_16x16x16bf16_1k(vf, pf[0][i], O[0][dt], 0, 0, 0);
                O[1][dt] = __builtin_amdgcn_mfma_f32_16x16x16bf16_1k(vf, pf[1][i], O[1][dt], 0, 0, 0);
            }
        }
        __syncthreads();   // protect Ks/Vs before next chunk's staging
    }

    // row sums: reduce across quads (same l16 = same q)
#pragma unroll
    for (int p = 0; p < 2; ++p) {
        lsum[p] += __shfl_xor(lsum[p], 16, 64);
        lsum[p] += __shfl_xor(lsum[p], 32, 64);
    }
    const float inv1 = 1.0f / lsum[0];
    const float inv2 = lam_s / lsum[1];

    // diff + RMSNorm over d (across regs+quads for fixed q=l16)
    float ssum = 0.f;
#pragma unroll
    for (int dt = 0; dt < 8; ++dt)
#pragma unroll
        for (int r = 0; r < 4; ++r) {
            float v = O[0][dt][r] * inv1 - O[1][dt][r] * inv2;
            O[0][dt][r] = v;
            ssum += v * v;
        }
    ssum += __shfl_xor(ssum, 16, 64);
    ssum += __shfl_xor(ssum, 32, 64);
    const float rms = rsqrtf(ssum * (1.0f / 128.0f) + 1e-5f) * (1.0f - LAMBDA_INIT_F);

#pragma unroll
    for (int dt = 0; dt < 8; ++dt) {
        float4 g4 = *(const float4*)&g[dt * 16 + quad * 4];
        u16x4 o;
        o[0] = f2b(O[0][dt][0] * rms * g4.x);
        o[1] = f2b(O[0][dt][1] * rms * g4.y);
        o[2] = f2b(O[0][dt][2] * rms * g4.z);
        o[3] = f2b(O[0][dt][3] * rms * g4.w);
        *(u16x4*)&Aout[(size_t)(q0 + w * 16 + l16) * 2048 + j * 128 + dt * 16 + quad * 4] = o;
    }
}

extern "C" void kernel_launch(void* const* d_in, const int* in_sizes, int n_in,
                              void* d_out, int out_size, void* d_ws, size_t ws_size,
                              hipStream_t stream) {
    const float* query = (const float*)d_in[0];
    const float* key   = (const float*)d_in[1];
    const float* value = (const float*)d_in[2];
    const float* Wq  = (const float*)d_in[5];
    const float* Wk  = (const float*)d_in[6];
    const float* Wv  = (const float*)d_in[7];
    const float* Wo  = (const float*)d_in[8];
    const float* lq1 = (const float*)d_in[9];
    const float* lk1 = (const float*)d_in[10];
    const float* lq2 = (const float*)d_in[11];
    const float* lk2 = (const float*)d_in[12];
    const float* g   = (const float*)d_in[13];

    char* ws = (char*)d_ws;
    const size_t MB = 1ull << 20;
    const size_t N4 = 4194304;  // 2048*2048
    unsigned short* qb  = (unsigned short*)(ws + 0 * MB);    // qb,kb contiguous (proj out z=0,1)
    unsigned short* vt  = (unsigned short*)(ws + 16 * MB);   // V^T (z=2 transposed epilogue)
    unsigned short* Aat = (unsigned short*)(ws + 24 * MB);
    unsigned short* Xq  = (unsigned short*)(ws + 32 * MB);   // Xq,Xk,Xv then Wq,Wk,Wv,Wo: 7 contiguous slabs

    // alpha = HD^-0.5 * log2(e): scores come out in log2 domain -> raw v_exp_f32 in diff_attn
    const float alpha_q = 0.125f * 1.44269504f;

    cvt7<<<dim3(2048, 7), dim3(256), 0, stream>>>(query, key, value, Wq, Wk, Wv, Wo, Xq);
    // q/k/v projections: 768 two-wave blocks -> 3 blocks/CU, balanced single pass
    gemm_proj<<<dim3(16, 16, 3), dim3(128), 0, stream>>>(Xq, Xq + 3 * N4, qb, vt, alpha_q);
    diff_attn<<<dim3(32, 16), dim3(256), 0, stream>>>(qb, qb + N4, vt, lq1, lk1, lq2, lk2, g, Aat);
    // output projection: 512 blocks (2/CU), full K, fp32 out
    gemm_out<<<dim3(32, 16), dim3(256), 0, stream>>>(Aat, Xq + 6 * N4, (float*)d_out);
}